// Round 1
// baseline (1921.736 us; speedup 1.0000x reference)
//
#include <hip/hip_runtime.h>
#include <hip/hip_bf16.h>

#define BB 32
#define CC 256
#define NN 4096

typedef __attribute__((ext_vector_type(8))) short short8;
typedef __attribute__((ext_vector_type(4))) float f32x4;

__device__ __forceinline__ unsigned short f2bf(float f) {
    union { float f; unsigned u; } v; v.f = f;
    unsigned r = v.u + 0x7FFFu + ((v.u >> 16) & 1u);   // RNE
    return (unsigned short)(r >> 16);
}

// ---------------- kernel 1: mean over B ----------------
__global__ __launch_bounds__(256) void mean_kernel(const float* __restrict__ x,
                                                   float* __restrict__ mean) {
    const int tid = blockIdx.x * 256 + threadIdx.x;   // 0 .. C*N/4-1
    const f32x4* xp = (const f32x4*)x;
    f32x4 s = {0.f, 0.f, 0.f, 0.f};
    const size_t base = (size_t)tid;                  // c*(N/4)+n4 == tid
    #pragma unroll
    for (int b = 0; b < BB; ++b) {
        f32x4 v = xp[(size_t)b * (CC * (NN / 4)) + base];
        s.x += v.x; s.y += v.y; s.z += v.z; s.w += v.w;
    }
    const float inv = 1.0f / 32.0f;
    f32x4 m = { s.x * inv, s.y * inv, s.z * inv, s.w * inv };
    ((f32x4*)mean)[tid] = m;
}

// ---------------- kernel 2: covariance ----------------
// tile: 32 c-rows x 32 d-rows x 16 locations. 256 threads = 4 waves (2x2 quadrants).
// LDS: bf16 panels [n(16)][row(32)][b(32)] with XOR-swizzled 8-element b-chunks.
__global__ __launch_bounds__(256, 2) void cov_kernel(const float* __restrict__ x,
                                                     const float* __restrict__ mean,
                                                     float* __restrict__ cov) {
    __shared__ __align__(16) unsigned short Ap[16 * 1024];
    __shared__ __align__(16) unsigned short Bp[16 * 1024];

    const int bx = blockIdx.x;        // (ct<<3)|dt
    const int n0 = blockIdx.y << 4;   // location tile base
    const int ct = bx >> 3, dt = bx & 7;
    const int c0 = ct << 5, d0 = dt << 5;
    const int t  = threadIdx.x;

    // ---- staging: global fp32 -> LDS bf16, swizzled ----
    {
        const int q  = t & 3;         // which 4-n chunk of the 16-n row
        const int rb = t >> 2;        // 0..63
        const int npanels = (ct == dt) ? 1 : 2;
        for (int p = 0; p < npanels; ++p) {
            const int r0 = p ? d0 : c0;
            unsigned short* P = p ? Bp : Ap;
            #pragma unroll 4
            for (int it = 0; it < 16; ++it) {
                const int rid = (it << 6) + rb;   // (cl,b) row id 0..1023
                const int cl = rid >> 5;
                const int b  = rid & 31;
                const f32x4 v = *(const f32x4*)(x + ((size_t)(b * CC + r0 + cl) * NN + n0 + (q << 2)));
                const int swz_cl = (cl >> 1) & 3;
                const int bc = b >> 3, bj = b & 7;
                unsigned short h[4] = { f2bf(v.x), f2bf(v.y), f2bf(v.z), f2bf(v.w) };
                #pragma unroll
                for (int i = 0; i < 4; ++i) {
                    const int n = (q << 2) + i;   // local n 0..15
                    const int chunk = (bc ^ swz_cl ^ (n >> 2)) & 3;
                    P[(n << 10) + (cl << 5) + (chunk << 3) + bj] = h[i];
                }
            }
        }
    }
    __syncthreads();

    // ---- MFMA: acc[n] = Xc[32x32] * Xd^T per location ----
    const int w = t >> 6, l = t & 63;
    const int qc = w >> 1, qd = w & 1;
    const int col = l & 15, kq = l >> 4;
    const unsigned short* Bu = (ct == dt) ? Ap : Bp;

    const int acl = (qc << 4) + col;            // A row (c-local): lane&15
    const int bcl = (qd << 4) + col;            // B row (d-local): lane&15
    const int aswz = kq ^ ((acl >> 1) & 3);
    const int bswz = kq ^ ((bcl >> 1) & 3);

    const f32x4 zero = {0.f, 0.f, 0.f, 0.f};
    f32x4 acc[16];
    #pragma unroll
    for (int n = 0; n < 16; ++n) {
        const int nz = n >> 2;
        const short8 af = *(const short8*)(Ap + (n << 10) + (acl << 5) + (((aswz ^ nz) & 3) << 3));
        const short8 bf = *(const short8*)(Bu + (n << 10) + (bcl << 5) + (((bswz ^ nz) & 3) << 3));
        acc[n] = __builtin_amdgcn_mfma_f32_16x16x32_bf16(af, bf, zero, 0, 0, 0);
    }

    // ---- epilogue: cov = acc/31 - (32/31)*mc*md + REG*I ----
    const int d  = d0 + (qd << 4) + col;            // C/D col = lane&15
    const int cb = c0 + (qc << 4) + (kq << 2);      // C/D row = (lane>>4)*4 + reg
    const float inv31 = 1.0f / 31.0f;
    const float k32 = 32.0f * inv31;
    f32x4 md[4];
    #pragma unroll
    for (int ch = 0; ch < 4; ++ch)
        md[ch] = *(const f32x4*)(mean + (size_t)d * NN + n0 + (ch << 2));
    #pragma unroll
    for (int r = 0; r < 4; ++r) {
        const int c = cb + r;
        const float diag = (c == d) ? 0.01f : 0.0f;
        float* out = cov + ((size_t)(c * CC + d) * NN + n0);
        #pragma unroll
        for (int ch = 0; ch < 4; ++ch) {
            const f32x4 mc = *(const f32x4*)(mean + (size_t)c * NN + n0 + (ch << 2));
            f32x4 o;
            o.x = acc[(ch << 2) + 0][r] * inv31 - k32 * mc.x * md[ch].x + diag;
            o.y = acc[(ch << 2) + 1][r] * inv31 - k32 * mc.y * md[ch].y + diag;
            o.z = acc[(ch << 2) + 2][r] * inv31 - k32 * mc.z * md[ch].z + diag;
            o.w = acc[(ch << 2) + 3][r] * inv31 - k32 * mc.w * md[ch].w + diag;
            *(f32x4*)(out + (ch << 2)) = o;
        }
    }
}

extern "C" void kernel_launch(void* const* d_in, const int* in_sizes, int n_in,
                              void* d_out, int out_size, void* d_ws, size_t ws_size,
                              hipStream_t stream) {
    const float* x = (const float*)d_in[0];
    float* meanp = (float*)d_out;                       // [C, N] = 1,048,576 floats
    float* covp  = (float*)d_out + (size_t)CC * NN;     // [C, C, N]
    mean_kernel<<<(CC * NN / 4) / 256, 256, 0, stream>>>(x, meanp);
    dim3 g(64, NN / 16);                                // 64 cd-tiles x 256 n-tiles
    cov_kernel<<<g, 256, 0, stream>>>(x, meanp, covp);
}